// Round 5
// baseline (3327.874 us; speedup 1.0000x reference)
//
#include <hip/hip_runtime.h>

#define BS    32
#define MDIM  256
#define NDIM  512
#define ITERS 1000
#define BLK   512
#define ALPHA 0.02f
#define BETA  0.02f

// R5: wave-autonomous iteration with FULL-IMAGE coalesced register poll.
// Each wave owns 16 G-rows (regs: acc[16][8], cols {64c+lane}) and polls the
// whole 512-word w image with 8 coalesced loads landing directly in the
// matvec's wr[c] layout. NO barriers / NO LDS in the loop: removes LDS stage,
// __syncthreads (whose vmcnt-drain waited on our own store's LLC ack), and
// sibling-wave skew. R1's flood is fixed: 8x4 fully-used lines per sample
// (32 line-reqs) vs R1's 8x32 strided (256) — under the LLC saturation knee.
// XCD-local mapping kept: batch = bid&31 -> batch's 4 wgs all == b (mod 8)
// (R4 broke this and paid 5x FETCH + 34% time).
#define NWG   128

// ---- LDS (PROLOGUE ONLY): A-tile [32][ATS=520] + b[32] ----
#define ATS      520
#define BT_OFF   (32 * ATS)
#define SMEM_FL  (BT_OFF + 32)          // 66,688 B

// Exchange slab: [2 parity][BS][512] floats, mantissa-tagged words (low 8
// bits = (k+1)&255): every 4B word self-validates (proven protocol). Agent-
// scope relaxed atomics only. Tag-gating bounds inter-wave drift to <2
// iters -> 2-parity overwrite safety unchanged at wave granularity.
#define SLAB_FL  (2 * BS * NDIM)

__device__ __forceinline__ unsigned ld_coh_u32(const void* p) {
  return __hip_atomic_load(reinterpret_cast<const unsigned*>(p),
                           __ATOMIC_RELAXED, __HIP_MEMORY_SCOPE_AGENT);
}
__device__ __forceinline__ void st_coh_u32(void* p, unsigned v) {
  __hip_atomic_store(reinterpret_cast<unsigned*>(p), v,
                     __ATOMIC_RELAXED, __HIP_MEMORY_SCOPE_AGENT);
}
__device__ __forceinline__ unsigned tagf(float v, unsigned tag) {
  return (__float_as_uint(v) & ~0xFFu) | tag;
}

__global__ __launch_bounds__(BLK, 1) void pdhg_kernel(
    const float* __restrict__ A, const float* __restrict__ Bvec,
    float* __restrict__ out, float* __restrict__ slab)
{
  __shared__ float smem[SMEM_FL];
  const int tid   = threadIdx.x;
  const int bid   = blockIdx.x;
  const int batch = bid & (BS - 1);      // XCD-local: all 4 wgs of a batch
  const int slice = bid >> 5;            //   share bid%8 under round-robin
  const int lane  = tid & 63;
  const int widx  = tid >> 6;            // wave in wg, 0..7
  const int rowbase = slice * 128 + widx * 16;   // wave's 16 G-rows
  const int row_own = lane & 15;                 // lane's row (4-redundant)
  const int i_own   = rowbase + row_own;

  // ================= PROLOGUE: G rows in regs, c = A^T b per-lane ==========
  // (byte-identical to R3's verified prologue)
  float acc[16][8];                      // acc[r][c] = G[rowbase+r][64c+lane]
#pragma unroll
  for (int r = 0; r < 16; ++r)
#pragma unroll
    for (int c = 0; c < 8; ++c) acc[r][c] = 0.f;
  float cacc = 0.f;                      // c[i_own], identical across redundant lanes

  const float* Ag = A + (size_t)batch * MDIM * NDIM;

  for (int mt = 0; mt < MDIM / 32; ++mt) {
#pragma unroll 4
    for (int q = 0; q < 8; ++q) {
      int f  = q * 512 + tid;            // float4 index in 32x512 tile
      int mm = f >> 7;
      int j  = (f & 127) << 2;
      float4 v = *reinterpret_cast<const float4*>(
          Ag + (size_t)(mt * 32 + mm) * NDIM + j);
      *reinterpret_cast<float4*>(&smem[mm * ATS + j]) = v;
    }
    if (tid < 32) smem[BT_OFF + tid] = Bvec[batch * MDIM + mt * 32 + tid];
    __syncthreads();

#pragma unroll 2
    for (int m = 0; m < 32; ++m) {
      const float* row = &smem[m * ATS];
      float4 a0 = *reinterpret_cast<const float4*>(row + rowbase);
      float4 a1 = *reinterpret_cast<const float4*>(row + rowbase + 4);
      float4 a2 = *reinterpret_cast<const float4*>(row + rowbase + 8);
      float4 a3 = *reinterpret_cast<const float4*>(row + rowbase + 12);
      float ai[16] = {a0.x,a0.y,a0.z,a0.w, a1.x,a1.y,a1.z,a1.w,
                      a2.x,a2.y,a2.z,a2.w, a3.x,a3.y,a3.z,a3.w};
      float aj[8];
#pragma unroll
      for (int c = 0; c < 8; ++c) aj[c] = row[64 * c + lane];  // 2/bank: free
      float bm  = smem[BT_OFF + m];
      float aio = row[i_own];            // broadcast within 16-lane groups
#pragma unroll
      for (int r = 0; r < 16; ++r)
#pragma unroll
        for (int c = 0; c < 8; ++c) acc[r][c] = fmaf(ai[r], aj[c], acc[r][c]);
      cacc = fmaf(aio, bm, cacc);
    }
    __syncthreads();
  }

  // ================= ITERATION (wave-autonomous, barrier/LDS-free) =========
  float x = 0.f, t = 0.f;
  float*       myslot = slab + batch * NDIM + i_own;  // store (lane<16), +parity
  const float* myrd   = slab + batch * NDIM + lane;   // poll base: words 64c+lane

  for (int k = 0; k < ITERS; ++k) {
    float y  = x - ALPHA * t;
    float xn = fmaxf(y - ALPHA, 0.f) - fmaxf(-y - ALPHA, 0.f);
    if (k == ITERS - 1) { x = xn; break; }

    const int      par = (k & 1) * BS * NDIM;
    const unsigned tag = (unsigned)(k + 1) & 0xFFu;
    float wv = 2.f * xn - x;
    x = xn;
    if (lane < 16) st_coh_u32(myslot + par, tagf(wv, tag));

    // full-image poll: 8 coalesced loads (4 fully-used lines each) land the
    // whole w image in the wave's registers, already in matvec layout.
    unsigned q[8];
    unsigned bad;
    do {
      bad = 0u;
#pragma unroll
      for (int c = 0; c < 8; ++c) {
        q[c] = ld_coh_u32(myrd + par + 64 * c);
        bad |= (q[c] ^ tag);
      }
      bad &= 0xFFu;
    } while (__any(bad));

    float wr[8];
#pragma unroll
    for (int c = 0; c < 8; ++c) wr[c] = __uint_as_float(q[c]);

    // S[r] = sum over this lane's cols; butterfly completes the 512-sum.
    float S[16];
#pragma unroll
    for (int r = 0; r < 16; ++r) {
      float p = acc[r][0] * wr[0];
#pragma unroll
      for (int c = 1; c < 8; ++c) p = fmaf(acc[r][c], wr[c], p);
      S[r] = p;
    }

    // value-halving butterfly (verified R3): after xor 1,2,4,8 lane holds row
    // (lane&15) summed over its 16-lane group; xor16+xor32 are single
    // commutative adds -> all 4 redundant lanes bit-identical.
    const bool b0 = (lane & 1), b1 = (lane & 2), b2 = (lane & 4), b3 = (lane & 8);
    float T[8];
#pragma unroll
    for (int i = 0; i < 8; ++i) {
      float keep = b0 ? S[2*i+1] : S[2*i];
      float send = b0 ? S[2*i]   : S[2*i+1];
      T[i] = keep + __shfl_xor(send, 1);
    }
    float U[4];
#pragma unroll
    for (int i = 0; i < 4; ++i) {
      float keep = b1 ? T[2*i+1] : T[2*i];
      float send = b1 ? T[2*i]   : T[2*i+1];
      U[i] = keep + __shfl_xor(send, 2);
    }
    float V[2];
#pragma unroll
    for (int i = 0; i < 2; ++i) {
      float keep = b2 ? U[2*i+1] : U[2*i];
      float send = b2 ? U[2*i]   : U[2*i+1];
      V[i] = keep + __shfl_xor(send, 4);
    }
    float Wv;
    {
      float keep = b3 ? V[1] : V[0];
      float send = b3 ? V[0] : V[1];
      Wv = keep + __shfl_xor(send, 8);
    }
    Wv += __shfl_xor(Wv, 16);
    Wv += __shfl_xor(Wv, 32);

    t += BETA * (Wv - cacc);             // t_{k+1} = t_k + beta*(G w - c)
  }

  // ---- epilogue: canonical lanes write x slice ----
  if (lane < 16) out[(size_t)batch * NDIM + i_own] = x;
}

extern "C" void kernel_launch(void* const* d_in, const int* in_sizes, int n_in,
                              void* d_out, int out_size, void* d_ws, size_t ws_size,
                              hipStream_t stream) {
  const float* A = (const float*)d_in[0];
  const float* b = (const float*)d_in[1];
  float* out  = (float*)d_out;
  float* slab = (float*)d_ws;                    // 128 KiB w-exchange slab

  hipMemsetAsync(d_ws, 0, SLAB_FL * sizeof(float), stream);  // tag 0 != 1,2

  void* args[] = {(void*)&A, (void*)&b, (void*)&out, (void*)&slab};
  hipLaunchCooperativeKernel((const void*)pdhg_kernel, dim3(NWG), dim3(BLK),
                             args, 0, stream);
}

// Round 6
// 1757.174 us; speedup vs baseline: 1.8939x; 1.8939x over previous
//
#include <hip/hip_runtime.h>

#define BS    32
#define MDIM  256
#define NDIM  512
#define ITERS 1000
#define BLK   512
#define ALPHA 0.02f
#define BETA  0.02f

// R6: flag-byte exchange protocol. Session-wide finding: spin-sample request
// rate into the LLC sets effective poll latency (R1/R5 at 8x R3's rate were
// both ~2x slower; R4's cross-XCD hops also lost). So: readers spin on ONE
// u32 flag word per batch (wave-coalesced same-address = 1 line/wave/sample,
// 4x less than R3) instead of 512 data words (4 lines/wave/sample). Writers:
// w-stores -> __syncthreads (compiler drains vmcnt -> stores acked at LLC)
// -> tid==0 byte-stores its wg's flag byte. Flag match => data visible; one
// validated read per thread fetches w. Data mantissa tags kept as
// belt-and-suspenders (validate loop passes first try when ordering holds).
#define NWG   128

// ---- LDS: A-tile [32][ATS=520] + b[32]; padded to 84KB -> 1 wg/CU ----
// (R3's 67KB allowed 2 wgs/CU -> different CU packing; suspect in its 9%
// regression vs baseline. Baseline ran 86016B; match it.)
#define ATS      520
#define BT_OFF   (32 * ATS)
#define SMEM_FL  21504                  // 86016 B

// Slab: [2 parity][BS][512] data floats (mantissa-tagged, proven protocol)
// + flag region: u32 flags[BS][2 parity][16 pad] (64B/slot, 128B/batch —
// no cross-batch line sharing). Byte s of a flag word belongs to wg-slice s.
// Slot-reuse safety: consecutive tags in a slot differ by 2 mod 256 (never
// equal); memset-0 != any first-use tag (parity0 first=1, parity1 first=2).
#define SLAB_FL   (2 * BS * NDIM)
#define FLAG_OFF  SLAB_FL               // u32 index into slab
#define WS_BYTES  (SLAB_FL * 4 + BS * 128)

__device__ __forceinline__ unsigned ld_coh_u32(const void* p) {
  return __hip_atomic_load(reinterpret_cast<const unsigned*>(p),
                           __ATOMIC_RELAXED, __HIP_MEMORY_SCOPE_AGENT);
}
__device__ __forceinline__ void st_coh_u32(void* p, unsigned v) {
  __hip_atomic_store(reinterpret_cast<unsigned*>(p), v,
                     __ATOMIC_RELAXED, __HIP_MEMORY_SCOPE_AGENT);
}
__device__ __forceinline__ void st_coh_u8(void* p, unsigned char v) {
  __hip_atomic_store(reinterpret_cast<unsigned char*>(p), v,
                     __ATOMIC_RELAXED, __HIP_MEMORY_SCOPE_AGENT);
}
__device__ __forceinline__ unsigned tagf(float v, unsigned tag) {
  return (__float_as_uint(v) & ~0xFFu) | tag;
}

__global__ __launch_bounds__(BLK, 1) void pdhg_kernel(
    const float* __restrict__ A, const float* __restrict__ Bvec,
    float* __restrict__ out, float* __restrict__ slab)
{
  __shared__ float smem[SMEM_FL];
  const int tid   = threadIdx.x;
  const int bid   = blockIdx.x;
  const int batch = bid & (BS - 1);      // XCD-local: a batch's 4 wgs all
  const int slice = bid >> 5;            //   share bid%8 (round-robin)
  const int lane  = tid & 63;
  const int widx  = tid >> 6;            // wave in wg, 0..7
  const int rowbase = slice * 128 + widx * 16;   // wave's 16 G-rows
  const int row_own = lane & 15;                 // lane's row (4-redundant)
  const int i_own   = rowbase + row_own;

  // ================= PROLOGUE: G rows in regs, c = A^T b (R3 verbatim) =====
  float acc[16][8];                      // acc[r][c] = G[rowbase+r][64c+lane]
#pragma unroll
  for (int r = 0; r < 16; ++r)
#pragma unroll
    for (int c = 0; c < 8; ++c) acc[r][c] = 0.f;
  float cacc = 0.f;

  const float* Ag = A + (size_t)batch * MDIM * NDIM;

  for (int mt = 0; mt < MDIM / 32; ++mt) {
#pragma unroll 4
    for (int q = 0; q < 8; ++q) {
      int f  = q * 512 + tid;            // float4 index in 32x512 tile
      int mm = f >> 7;
      int j  = (f & 127) << 2;
      float4 v = *reinterpret_cast<const float4*>(
          Ag + (size_t)(mt * 32 + mm) * NDIM + j);
      *reinterpret_cast<float4*>(&smem[mm * ATS + j]) = v;
    }
    if (tid < 32) smem[BT_OFF + tid] = Bvec[batch * MDIM + mt * 32 + tid];
    __syncthreads();

#pragma unroll 2
    for (int m = 0; m < 32; ++m) {
      const float* row = &smem[m * ATS];
      float4 a0 = *reinterpret_cast<const float4*>(row + rowbase);
      float4 a1 = *reinterpret_cast<const float4*>(row + rowbase + 4);
      float4 a2 = *reinterpret_cast<const float4*>(row + rowbase + 8);
      float4 a3 = *reinterpret_cast<const float4*>(row + rowbase + 12);
      float ai[16] = {a0.x,a0.y,a0.z,a0.w, a1.x,a1.y,a1.z,a1.w,
                      a2.x,a2.y,a2.z,a2.w, a3.x,a3.y,a3.z,a3.w};
      float aj[8];
#pragma unroll
      for (int c = 0; c < 8; ++c) aj[c] = row[64 * c + lane];  // 2/bank: free
      float bm  = smem[BT_OFF + m];
      float aio = row[i_own];
#pragma unroll
      for (int r = 0; r < 16; ++r)
#pragma unroll
        for (int c = 0; c < 8; ++c) acc[r][c] = fmaf(ai[r], aj[c], acc[r][c]);
      cacc = fmaf(aio, bm, cacc);
    }
    __syncthreads();
  }

  // ================= ITERATION ============================================
  float x = 0.f, t = 0.f;
  float*       myslot = slab + batch * NDIM + i_own;  // store (lane<16), +parity
  const float* myrd   = slab + batch * NDIM + tid;    // own data word
  unsigned* flagb = reinterpret_cast<unsigned*>(slab) + FLAG_OFF + batch * 32;

  for (int k = 0; k < ITERS; ++k) {
    float y  = x - ALPHA * t;
    float xn = fmaxf(y - ALPHA, 0.f) - fmaxf(-y - ALPHA, 0.f);
    if (k == ITERS - 1) { x = xn; break; }

    const int      par = (k & 1) * BS * NDIM;
    const unsigned tag = (unsigned)(k + 1) & 0xFFu;
    float wv = 2.f * xn - x;
    x = xn;
    if (lane < 16) st_coh_u32(myslot + par, tagf(wv, tag));

    // barrier = s_waitcnt vmcnt(0) + s_barrier: on exit, ALL this wg's
    // w-stores are acked at the coherence point. Then one flag byte-store
    // announces the whole 128-word slice at once.
    __syncthreads();
    unsigned* flagw = flagb + (k & 1) * 16;
    if (tid == 0) st_coh_u8(reinterpret_cast<unsigned char*>(flagw) + slice,
                            (unsigned char)tag);

    // flag spin: one same-address load per wave per sample (1 line/wave).
    const unsigned exp4 = tag * 0x01010101u;
    unsigned fv;
    do { fv = ld_coh_u32(flagw); } while (fv != exp4);

    // data fetch: flag implies visibility -> validate loop passes first try.
    unsigned q;
    do { q = ld_coh_u32(myrd + par); } while ((q ^ tag) & 0xFFu);
    smem[tid] = __uint_as_float(q);
    __syncthreads();

    float wr[8];
#pragma unroll
    for (int c = 0; c < 8; ++c) wr[c] = smem[64 * c + lane];  // 2/bank: free

    float S[16];
#pragma unroll
    for (int r = 0; r < 16; ++r) {
      float p = acc[r][0] * wr[0];
#pragma unroll
      for (int c = 1; c < 8; ++c) p = fmaf(acc[r][c], wr[c], p);
      S[r] = p;
    }

    // value-halving butterfly (verified R3): final stages are single
    // commutative adds -> all 4 redundant lanes bit-identical.
    const bool b0 = (lane & 1), b1 = (lane & 2), b2 = (lane & 4), b3 = (lane & 8);
    float T[8];
#pragma unroll
    for (int i = 0; i < 8; ++i) {
      float keep = b0 ? S[2*i+1] : S[2*i];
      float send = b0 ? S[2*i]   : S[2*i+1];
      T[i] = keep + __shfl_xor(send, 1);
    }
    float U[4];
#pragma unroll
    for (int i = 0; i < 4; ++i) {
      float keep = b1 ? T[2*i+1] : T[2*i];
      float send = b1 ? T[2*i]   : T[2*i+1];
      U[i] = keep + __shfl_xor(send, 2);
    }
    float V[2];
#pragma unroll
    for (int i = 0; i < 2; ++i) {
      float keep = b2 ? U[2*i+1] : U[2*i];
      float send = b2 ? U[2*i]   : U[2*i+1];
      V[i] = keep + __shfl_xor(send, 4);
    }
    float Wv;
    {
      float keep = b3 ? V[1] : V[0];
      float send = b3 ? V[0] : V[1];
      Wv = keep + __shfl_xor(send, 8);
    }
    Wv += __shfl_xor(Wv, 16);
    Wv += __shfl_xor(Wv, 32);

    t += BETA * (Wv - cacc);             // t_{k+1} = t_k + beta*(G w - c)
  }

  // ---- epilogue: canonical lanes write x slice ----
  if (lane < 16) out[(size_t)batch * NDIM + i_own] = x;
}

extern "C" void kernel_launch(void* const* d_in, const int* in_sizes, int n_in,
                              void* d_out, int out_size, void* d_ws, size_t ws_size,
                              hipStream_t stream) {
  const float* A = (const float*)d_in[0];
  const float* b = (const float*)d_in[1];
  float* out  = (float*)d_out;
  float* slab = (float*)d_ws;            // 128 KiB data + 4 KiB flags

  hipMemsetAsync(d_ws, 0, WS_BYTES, stream);   // tag 0 != any first-use tag

  void* args[] = {(void*)&A, (void*)&b, (void*)&out, (void*)&slab};
  hipLaunchCooperativeKernel((const void*)pdhg_kernel, dim3(NWG), dim3(BLK),
                             args, 0, stream);
}